// Round 1
// baseline (1546.794 us; speedup 1.0000x reference)
//
#include <hip/hip_runtime.h>

#define NN 100000      // nodes
#define NE 1600000     // edges
#define NF 128         // input features
#define H  64          // hidden channels
#define NG 4096        // graphs

// ---------------- degree / dinv ----------------
__global__ __launch_bounds__(256) void k_degree(const int* __restrict__ dst,
                                                float* __restrict__ deg) {
  int e = blockIdx.x * blockDim.x + threadIdx.x;
  if (e < NE) atomicAdd(&deg[dst[e]], 1.0f);
}

__global__ __launch_bounds__(256) void k_dinv(float* __restrict__ deg) {
  int i = blockIdx.x * blockDim.x + threadIdx.x;
  if (i < NN) deg[i] = 1.0f / sqrtf(deg[i] + 1.0f);
}

// ---------------- node GEMM: out[n,0..63] = in[n,:] @ W[CI,64] ----------------
template <int CI>
__global__ __launch_bounds__(256) void k_gemm(const float* __restrict__ in,
                                              const float* __restrict__ W,
                                              float* __restrict__ out) {
  __shared__ float wl[CI * 64];
  for (int i = threadIdx.x; i < CI * 64; i += blockDim.x) wl[i] = W[i];
  __syncthreads();
  const int col = threadIdx.x & 63;
  const int wv  = threadIdx.x >> 6;  // 0..3, each wave does 4 nodes
  for (int chunk = blockIdx.x * 16; chunk < NN; chunk += gridDim.x * 16) {
    const int n0 = chunk + wv * 4;
    const float* r0 = in + (size_t)n0 * CI;
    const float* r1 = r0 + CI;
    const float* r2 = r1 + CI;
    const float* r3 = r2 + CI;
    float a0 = 0.f, a1 = 0.f, a2 = 0.f, a3 = 0.f;
#pragma unroll 8
    for (int ci = 0; ci < CI; ++ci) {
      const float w = wl[ci * 64 + col];
      a0 = fmaf(r0[ci], w, a0);
      a1 = fmaf(r1[ci], w, a1);
      a2 = fmaf(r2[ci], w, a2);
      a3 = fmaf(r3[ci], w, a3);
    }
    const size_t o = (size_t)n0 * 64 + col;
    out[o]       = a0;
    out[o + 64]  = a1;
    out[o + 128] = a2;
    out[o + 192] = a3;
  }
}

// ---------------- edge scatter: agg[dst] += coef * hw[src] ----------------
__global__ __launch_bounds__(256) void k_scatter(const float* __restrict__ hw,
                                                 float* __restrict__ agg,
                                                 const int* __restrict__ src,
                                                 const int* __restrict__ dst,
                                                 const float* __restrict__ dinv) {
  const long long t = (long long)blockIdx.x * blockDim.x + threadIdx.x;
  const int e = (int)(t >> 6);
  const int c = (int)(t & 63);
  if (e < NE) {
    const int s = src[e];
    const int d = dst[e];
    const float coef = dinv[s] * dinv[d];
    atomicAdd(&agg[(size_t)d * 64 + c], coef * hw[(size_t)s * 64 + c]);
  }
}

// ---------------- layer-0 finalize: h = relu(agg + hw*dinv^2 + b0) ----------------
__global__ __launch_bounds__(256) void k_fin0(const float* __restrict__ agg,
                                              const float* __restrict__ hw,
                                              const float* __restrict__ dinv,
                                              const float* __restrict__ bias,
                                              float* __restrict__ h) {
  const int t = blockIdx.x * blockDim.x + threadIdx.x;
  if (t < NN * 64) {
    const int n = t >> 6, c = t & 63;
    const float di = dinv[n];
    h[t] = fmaxf(agg[t] + hw[t] * di * di + bias[c], 0.0f);
  }
}

// ------- inner-layer finalize (fused skip GEMM, in-place on h) -------
// h[n,c] = relu(agg[n,c] + hw[n,c]*dinv^2 + convB[c]) + h[n,:]@skipW[:,c] + skipB[c]
__global__ __launch_bounds__(256) void k_fin_skip(const float* __restrict__ agg,
                                                  const float* __restrict__ hw,
                                                  const float* __restrict__ dinv,
                                                  const float* __restrict__ convB,
                                                  const float* __restrict__ skipW,
                                                  const float* __restrict__ skipB,
                                                  float* __restrict__ h) {
  __shared__ float swl[64 * 64];
  for (int i = threadIdx.x; i < 64 * 64; i += blockDim.x) swl[i] = skipW[i];
  __syncthreads();
  const int col = threadIdx.x & 63;
  const int wv  = threadIdx.x >> 6;  // one wave == one node
  for (int chunk = blockIdx.x * 4; chunk < NN; chunk += gridDim.x * 4) {
    const int n = chunk + wv;
    const float* row = h + (size_t)n * 64;
    float acc = 0.f;
#pragma unroll 8
    for (int ci = 0; ci < 64; ++ci) acc = fmaf(row[ci], swl[ci * 64 + col], acc);
    const size_t idx = (size_t)n * 64 + col;
    const float di = dinv[n];
    const float v =
        fmaxf(agg[idx] + hw[idx] * di * di + convB[col], 0.0f) + acc + skipB[col];
    // safe in-place: this wave is the only reader of row n, and all lanes
    // finish reading the row (loop above) before any lane stores.
    h[idx] = v;
  }
}

// ---------------- mean-pool scatter ----------------
__global__ __launch_bounds__(256) void k_pool(const float* __restrict__ h,
                                              const int* __restrict__ b,
                                              float* __restrict__ pool,
                                              float* __restrict__ cnt) {
  const int t = blockIdx.x * blockDim.x + threadIdx.x;
  if (t < NN * 64) {
    const int n = t >> 6, c = t & 63;
    const int g = b[n];
    atomicAdd(&pool[(size_t)g * 64 + c], h[t]);
    if (c == 0) atomicAdd(&cnt[g], 1.0f);
  }
}

// ---------------- MLP head: out[g] = relu(pool/cnt @ lin1W + lin1b) @ lin2W + lin2b
__global__ __launch_bounds__(64) void k_head(const float* __restrict__ pool,
                                             const float* __restrict__ cnt,
                                             const float* __restrict__ lin1W,
                                             const float* __restrict__ lin1b,
                                             const float* __restrict__ lin2W,
                                             const float* __restrict__ lin2b,
                                             float* __restrict__ out) {
  const int g = blockIdx.x;
  const int lane = threadIdx.x;  // blockDim 64, lanes 32..63 contribute 0
  const float c = fmaxf(cnt[g], 1.0f);
  float r = 0.f;
  if (lane < 32) {
    float s = lin1b[lane];
    const float* p = pool + (size_t)g * 64;
#pragma unroll 8
    for (int ci = 0; ci < 64; ++ci) s = fmaf(p[ci] / c, lin1W[ci * 32 + lane], s);
    r = fmaxf(s, 0.0f) * lin2W[lane];
  }
  for (int off = 32; off > 0; off >>= 1) r += __shfl_down(r, off, 64);
  if (lane == 0) out[g] = r + lin2b[0];
}

extern "C" void kernel_launch(void* const* d_in, const int* in_sizes, int n_in,
                              void* d_out, int out_size, void* d_ws, size_t ws_size,
                              hipStream_t stream) {
  const float* x     = (const float*)d_in[0];
  const int*   src   = (const int*)d_in[1];            // e_idx[0]
  const int*   dst   = ((const int*)d_in[1]) + NE;     // e_idx[1]
  const int*   b     = (const int*)d_in[2];
  const float* w0    = (const float*)d_in[3];
  const float* b0    = (const float*)d_in[4];
  const float* convW = (const float*)d_in[5];
  const float* convB = (const float*)d_in[6];
  const float* skipW = (const float*)d_in[7];
  const float* skipB = (const float*)d_in[8];
  const float* lin1W = (const float*)d_in[9];
  const float* lin1b = (const float*)d_in[10];
  const float* lin2W = (const float*)d_in[11];
  const float* lin2b = (const float*)d_in[12];
  float* out = (float*)d_out;

  float* ws   = (float*)d_ws;
  float* dinv = ws;                       // NN floats (padded to 102400)
  float* hA   = ws + 102400;              // h      [NN,64]
  float* hB   = hA + (size_t)NN * 64;     // h @ W  [NN,64]
  float* hC   = hB + (size_t)NN * 64;     // agg    [NN,64]
  float* pool = hC + (size_t)NN * 64;     // [NG,64]
  float* cnt  = pool + (size_t)NG * 64;   // [NG]

  // degrees -> dinv
  hipMemsetAsync(dinv, 0, NN * sizeof(float), stream);
  k_degree<<<(NE + 255) / 256, 256, 0, stream>>>(dst, dinv);
  k_dinv<<<(NN + 255) / 256, 256, 0, stream>>>(dinv);

  // layer 0: hB = x @ w0 ; hC = scatter ; hA = relu(hC + hB*dinv^2 + b0)
  k_gemm<NF><<<512, 256, 0, stream>>>(x, w0, hB);
  hipMemsetAsync(hC, 0, (size_t)NN * 64 * sizeof(float), stream);
  k_scatter<<<(int)(((long long)NE * 64) / 256), 256, 0, stream>>>(hB, hC, src, dst, dinv);
  k_fin0<<<(NN * 64) / 256, 256, 0, stream>>>(hC, hB, dinv, b0, hA);

  // layers 1..2
  for (int i = 0; i < 2; ++i) {
    k_gemm<H><<<512, 256, 0, stream>>>(hA, convW + (size_t)i * H * H, hB);
    hipMemsetAsync(hC, 0, (size_t)NN * 64 * sizeof(float), stream);
    k_scatter<<<(int)(((long long)NE * 64) / 256), 256, 0, stream>>>(hB, hC, src, dst, dinv);
    k_fin_skip<<<2048, 256, 0, stream>>>(hC, hB, dinv, convB + (size_t)i * H,
                                         skipW + (size_t)i * H * H,
                                         skipB + (size_t)i * H, hA);
  }

  // mean pool + head
  hipMemsetAsync(pool, 0, ((size_t)NG * 64 + NG) * sizeof(float), stream);
  k_pool<<<(NN * 64) / 256, 256, 0, stream>>>(hA, b, pool, cnt);
  k_head<<<NG, 64, 0, stream>>>(pool, cnt, lin1W, lin1b, lin2W, lin2b, out);
}

// Round 2
// 955.343 us; speedup vs baseline: 1.6191x; 1.6191x over previous
//
#include <hip/hip_runtime.h>

#define NN 100000      // nodes
#define NE 1600000     // edges
#define NF 128         // input features
#define H  64          // hidden channels
#define NG 4096        // graphs
#define SCAN_B 512
#define NB ((NN + SCAN_B - 1) / SCAN_B)   // 196 scan blocks

// ---------------- degree histogram (int) ----------------
__global__ __launch_bounds__(256) void k_hist(const int* __restrict__ dst,
                                              int* __restrict__ cnt) {
  int e = blockIdx.x * blockDim.x + threadIdx.x;
  if (e < NE) atomicAdd(&cnt[dst[e]], 1);
}

__global__ __launch_bounds__(256) void k_dinv(const int* __restrict__ cnt,
                                              float* __restrict__ dinv) {
  int i = blockIdx.x * blockDim.x + threadIdx.x;
  if (i < NN) dinv[i] = 1.0f / sqrtf((float)cnt[i] + 1.0f);
}

// ---------------- 3-phase exclusive scan of cnt -> row_ptr ----------------
__global__ __launch_bounds__(SCAN_B) void k_scan_a(const int* __restrict__ cnt,
                                                   int* __restrict__ incl,
                                                   int* __restrict__ bsum) {
  __shared__ int sh[SCAN_B];
  const int i = blockIdx.x * SCAN_B + threadIdx.x;
  int v = (i < NN) ? cnt[i] : 0;
  sh[threadIdx.x] = v;
  __syncthreads();
  for (int off = 1; off < SCAN_B; off <<= 1) {
    int add = (threadIdx.x >= off) ? sh[threadIdx.x - off] : 0;
    __syncthreads();
    sh[threadIdx.x] += add;
    __syncthreads();
  }
  if (i < NN) incl[i] = sh[threadIdx.x];
  if (threadIdx.x == SCAN_B - 1) bsum[blockIdx.x] = sh[SCAN_B - 1];
}

__global__ __launch_bounds__(256) void k_scan_b(int* __restrict__ bsum,
                                                int* __restrict__ boff) {
  __shared__ int sh[256];
  const int t = threadIdx.x;
  int v = (t < NB) ? bsum[t] : 0;
  sh[t] = v;
  __syncthreads();
  for (int off = 1; off < 256; off <<= 1) {
    int add = (t >= off) ? sh[t - off] : 0;
    __syncthreads();
    sh[t] += add;
    __syncthreads();
  }
  if (t < NB) boff[t] = sh[t] - v;  // exclusive
}

__global__ __launch_bounds__(SCAN_B) void k_scan_c(const int* __restrict__ cnt,
                                                   const int* __restrict__ incl,
                                                   const int* __restrict__ boff,
                                                   int* __restrict__ row_ptr,
                                                   int* __restrict__ cursor) {
  const int i = blockIdx.x * SCAN_B + threadIdx.x;
  if (i < NN) {
    const int start = incl[i] + boff[blockIdx.x] - cnt[i];
    row_ptr[i] = start;
    cursor[i] = start;
  }
  if (i == 0) row_ptr[NN] = NE;
}

// ---------------- CSR fill: packed (src, coef) per slot ----------------
__global__ __launch_bounds__(256) void k_fill(const int* __restrict__ src,
                                              const int* __restrict__ dst,
                                              const float* __restrict__ dinv,
                                              int* __restrict__ cursor,
                                              float2* __restrict__ csr) {
  int e = blockIdx.x * blockDim.x + threadIdx.x;
  if (e < NE) {
    const int s = src[e], d = dst[e];
    const int pos = atomicAdd(&cursor[d], 1);
    csr[pos] = make_float2(__int_as_float(s), dinv[s] * dinv[d]);
  }
}

// ---------------- node GEMM: out[n,0..63] = in[n,:] @ W[CI,64] ----------------
template <int CI>
__global__ __launch_bounds__(256) void k_gemm(const float* __restrict__ in,
                                              const float* __restrict__ W,
                                              float* __restrict__ out) {
  __shared__ float wl[CI * 64];
  for (int i = threadIdx.x; i < CI * 64; i += blockDim.x) wl[i] = W[i];
  __syncthreads();
  const int col = threadIdx.x & 63;
  const int wv  = threadIdx.x >> 6;  // 0..3, each wave does 4 nodes
  for (int chunk = blockIdx.x * 16; chunk < NN; chunk += gridDim.x * 16) {
    const int n0 = chunk + wv * 4;
    const float* r0 = in + (size_t)n0 * CI;
    const float* r1 = r0 + CI;
    const float* r2 = r1 + CI;
    const float* r3 = r2 + CI;
    float a0 = 0.f, a1 = 0.f, a2 = 0.f, a3 = 0.f;
#pragma unroll 8
    for (int ci = 0; ci < CI; ++ci) {
      const float w = wl[ci * 64 + col];
      a0 = fmaf(r0[ci], w, a0);
      a1 = fmaf(r1[ci], w, a1);
      a2 = fmaf(r2[ci], w, a2);
      a3 = fmaf(r3[ci], w, a3);
    }
    const size_t o = (size_t)n0 * 64 + col;
    out[o]       = a0;
    out[o + 64]  = a1;
    out[o + 128] = a2;
    out[o + 192] = a3;
  }
}

// ------- fused CSR aggregation + finalize (+optional skip GEMM, in place) ----
// SKIP=false: h_out[n,c] = relu(sum + hw[n,c]*di^2 + bias[c])          (-> out)
// SKIP=true : h[n,c]     = relu(sum + hw[n,c]*di^2 + bias[c])
//                          + h[n,:]@skipW[:,c] + skipB[c]              (in place)
template <bool SKIP>
__global__ __launch_bounds__(256) void k_agg(const float* __restrict__ hw,
                                             const float2* __restrict__ csr,
                                             const int* __restrict__ row_ptr,
                                             const float* __restrict__ dinv,
                                             const float* __restrict__ bias,
                                             const float* __restrict__ skipW,
                                             const float* __restrict__ skipB,
                                             float* __restrict__ h) {
  __shared__ float swl[SKIP ? 64 * 64 : 64];
  if (SKIP) {
    for (int i = threadIdx.x; i < 64 * 64; i += blockDim.x) swl[i] = skipW[i];
    __syncthreads();
  }
  const int col = threadIdx.x & 63;
  const int wv  = threadIdx.x >> 6;  // one wave == one node
  for (int n = blockIdx.x * 4 + wv; n < NN; n += gridDim.x * 4) {
    const int beg = row_ptr[n], end = row_ptr[n + 1];
    float acc = 0.f;
    for (int j = beg; j < end; ++j) {
      const float2 p = csr[j];                     // wave-broadcast 8B load
      const int s = __float_as_int(p.x);
      acc = fmaf(p.y, hw[(size_t)s * 64 + col], acc);  // coalesced 256B row
    }
    const size_t idx = (size_t)n * 64 + col;
    const float di = dinv[n];
    float v = fmaxf(acc + hw[idx] * di * di + bias[col], 0.0f);
    if (SKIP) {
      const float* row = h + (size_t)n * 64;
      float sk = skipB[col];
#pragma unroll 8
      for (int ci = 0; ci < 64; ++ci) sk = fmaf(row[ci], swl[ci * 64 + col], sk);
      v += sk;  // all lanes finished reading row before any lane stores
    }
    h[idx] = v;
  }
}

// ---------------- mean-pool scatter ----------------
__global__ __launch_bounds__(256) void k_pool(const float* __restrict__ h,
                                              const int* __restrict__ b,
                                              float* __restrict__ pool,
                                              float* __restrict__ cnt) {
  const int t = blockIdx.x * blockDim.x + threadIdx.x;
  if (t < NN * 64) {
    const int n = t >> 6, c = t & 63;
    const int g = b[n];
    atomicAdd(&pool[(size_t)g * 64 + c], h[t]);
    if (c == 0) atomicAdd(&cnt[g], 1.0f);
  }
}

// ---------------- MLP head ----------------
__global__ __launch_bounds__(64) void k_head(const float* __restrict__ pool,
                                             const float* __restrict__ cnt,
                                             const float* __restrict__ lin1W,
                                             const float* __restrict__ lin1b,
                                             const float* __restrict__ lin2W,
                                             const float* __restrict__ lin2b,
                                             float* __restrict__ out) {
  const int g = blockIdx.x;
  const int lane = threadIdx.x;
  const float c = fmaxf(cnt[g], 1.0f);
  float r = 0.f;
  if (lane < 32) {
    float s = lin1b[lane];
    const float* p = pool + (size_t)g * 64;
#pragma unroll 8
    for (int ci = 0; ci < 64; ++ci) s = fmaf(p[ci] / c, lin1W[ci * 32 + lane], s);
    r = fmaxf(s, 0.0f) * lin2W[lane];
  }
  for (int off = 32; off > 0; off >>= 1) r += __shfl_down(r, off, 64);
  if (lane == 0) out[g] = r + lin2b[0];
}

extern "C" void kernel_launch(void* const* d_in, const int* in_sizes, int n_in,
                              void* d_out, int out_size, void* d_ws, size_t ws_size,
                              hipStream_t stream) {
  const float* x     = (const float*)d_in[0];
  const int*   src   = (const int*)d_in[1];            // e_idx[0]
  const int*   dst   = ((const int*)d_in[1]) + NE;     // e_idx[1]
  const int*   b     = (const int*)d_in[2];
  const float* w0    = (const float*)d_in[3];
  const float* b0    = (const float*)d_in[4];
  const float* convW = (const float*)d_in[5];
  const float* convB = (const float*)d_in[6];
  const float* skipW = (const float*)d_in[7];
  const float* skipB = (const float*)d_in[8];
  const float* lin1W = (const float*)d_in[9];
  const float* lin1b = (const float*)d_in[10];
  const float* lin2W = (const float*)d_in[11];
  const float* lin2b = (const float*)d_in[12];
  float* out = (float*)d_out;

  // ---- workspace layout (4-byte units, 102400-padded node arrays) ----
  char* w = (char*)d_ws;
  const size_t NPAD = 102400;
  int*    cnt     = (int*)w;                 w += NPAD * 4;
  float*  dinv    = (float*)w;               w += NPAD * 4;
  int*    row_ptr = (int*)w;                 w += NPAD * 4;   // NN+1 used
  int*    cursor  = (int*)w;                 w += NPAD * 4;
  int*    incl    = (int*)w;                 w += NPAD * 4;
  int*    bsum    = (int*)w;                 w += 512 * 4;
  int*    boff    = (int*)w;                 w += 512 * 4;
  float2* csr     = (float2*)w;              w += (size_t)NE * 8;
  float*  hA      = (float*)w;               w += (size_t)NN * 64 * 4;
  float*  hB      = (float*)w;               w += (size_t)NN * 64 * 4;
  float*  pool    = (float*)w;               w += (size_t)NG * 64 * 4;
  float*  pcnt    = (float*)w;               w += (size_t)NG * 4;

  const int EB = (NE + 255) / 256;

  // ---- CSR build (once per launch) ----
  hipMemsetAsync(cnt, 0, NN * sizeof(int), stream);
  k_hist<<<EB, 256, 0, stream>>>(dst, cnt);
  k_dinv<<<(NN + 255) / 256, 256, 0, stream>>>(cnt, dinv);
  k_scan_a<<<NB, SCAN_B, 0, stream>>>(cnt, incl, bsum);
  k_scan_b<<<1, 256, 0, stream>>>(bsum, boff);
  k_scan_c<<<NB, SCAN_B, 0, stream>>>(cnt, incl, boff, row_ptr, cursor);
  k_fill<<<EB, 256, 0, stream>>>(src, dst, dinv, cursor, csr);

  // ---- layer 0 ----
  k_gemm<NF><<<512, 256, 0, stream>>>(x, w0, hB);
  k_agg<false><<<2048, 256, 0, stream>>>(hB, csr, row_ptr, dinv, b0,
                                         nullptr, nullptr, hA);
  // ---- layers 1..2 (skip fused, in place on hA) ----
  for (int i = 0; i < 2; ++i) {
    k_gemm<H><<<512, 256, 0, stream>>>(hA, convW + (size_t)i * H * H, hB);
    k_agg<true><<<2048, 256, 0, stream>>>(hB, csr, row_ptr, dinv,
                                          convB + (size_t)i * H,
                                          skipW + (size_t)i * H * H,
                                          skipB + (size_t)i * H, hA);
  }

  // ---- mean pool + head ----
  hipMemsetAsync(pool, 0, ((size_t)NG * 64 + NG) * sizeof(float), stream);
  k_pool<<<(NN * 64) / 256, 256, 0, stream>>>(hA, b, pool, pcnt);
  k_head<<<NG, 64, 0, stream>>>(pool, pcnt, lin1W, lin1b, lin2W, lin2b, out);
}

// Round 3
// 691.481 us; speedup vs baseline: 2.2369x; 1.3816x over previous
//
#include <hip/hip_runtime.h>

#define NN 100000      // nodes
#define NE 1600000     // edges
#define NF 128         // input features
#define H  64          // hidden channels
#define NG 4096        // graphs
#define SCAN_B 512
#define NB ((NN + SCAN_B - 1) / SCAN_B)   // 196 scan blocks

// ---------------- degree histogram (int) ----------------
__global__ __launch_bounds__(256) void k_hist(const int* __restrict__ dst,
                                              int* __restrict__ cnt) {
  int e = blockIdx.x * blockDim.x + threadIdx.x;
  if (e < NE) atomicAdd(&cnt[dst[e]], 1);
}

__global__ __launch_bounds__(256) void k_dinv(const int* __restrict__ cnt,
                                              float* __restrict__ dinv) {
  int i = blockIdx.x * blockDim.x + threadIdx.x;
  if (i < NN) dinv[i] = 1.0f / sqrtf((float)cnt[i] + 1.0f);
}

// ---------------- 3-phase exclusive scan of cnt -> row_ptr ----------------
__global__ __launch_bounds__(SCAN_B) void k_scan_a(const int* __restrict__ cnt,
                                                   int* __restrict__ incl,
                                                   int* __restrict__ bsum) {
  __shared__ int sh[SCAN_B];
  const int i = blockIdx.x * SCAN_B + threadIdx.x;
  int v = (i < NN) ? cnt[i] : 0;
  sh[threadIdx.x] = v;
  __syncthreads();
  for (int off = 1; off < SCAN_B; off <<= 1) {
    int add = (threadIdx.x >= off) ? sh[threadIdx.x - off] : 0;
    __syncthreads();
    sh[threadIdx.x] += add;
    __syncthreads();
  }
  if (i < NN) incl[i] = sh[threadIdx.x];
  if (threadIdx.x == SCAN_B - 1) bsum[blockIdx.x] = sh[SCAN_B - 1];
}

__global__ __launch_bounds__(256) void k_scan_b(int* __restrict__ bsum,
                                                int* __restrict__ boff) {
  __shared__ int sh[256];
  const int t = threadIdx.x;
  int v = (t < NB) ? bsum[t] : 0;
  sh[t] = v;
  __syncthreads();
  for (int off = 1; off < 256; off <<= 1) {
    int add = (t >= off) ? sh[t - off] : 0;
    __syncthreads();
    sh[t] += add;
    __syncthreads();
  }
  if (t < NB) boff[t] = sh[t] - v;  // exclusive
}

__global__ __launch_bounds__(SCAN_B) void k_scan_c(const int* __restrict__ cnt,
                                                   const int* __restrict__ incl,
                                                   const int* __restrict__ boff,
                                                   int* __restrict__ row_ptr,
                                                   int* __restrict__ cursor) {
  const int i = blockIdx.x * SCAN_B + threadIdx.x;
  if (i < NN) {
    const int start = incl[i] + boff[blockIdx.x] - cnt[i];
    row_ptr[i] = start;
    cursor[i] = start;
  }
  if (i == 0) row_ptr[NN] = NE;
}

// ---------------- CSR fill: packed (src, coef) per slot ----------------
__global__ __launch_bounds__(256) void k_fill(const int* __restrict__ src,
                                              const int* __restrict__ dst,
                                              const float* __restrict__ dinv,
                                              int* __restrict__ cursor,
                                              float2* __restrict__ csr) {
  int e = blockIdx.x * blockDim.x + threadIdx.x;
  if (e < NE) {
    const int s = src[e], d = dst[e];
    const int pos = atomicAdd(&cursor[d], 1);
    csr[pos] = make_float2(__int_as_float(s), dinv[s] * dinv[d]);
  }
}

// ---------------- node GEMM: out[n,0..63] = in[n,:] @ W[CI,64] ----------------
template <int CI>
__global__ __launch_bounds__(256) void k_gemm(const float* __restrict__ in,
                                              const float* __restrict__ W,
                                              float* __restrict__ out) {
  __shared__ float wl[CI * 64];
  for (int i = threadIdx.x; i < CI * 64; i += blockDim.x) wl[i] = W[i];
  __syncthreads();
  const int col = threadIdx.x & 63;
  const int wv  = threadIdx.x >> 6;  // 0..3, each wave does 4 nodes
  for (int chunk = blockIdx.x * 16; chunk < NN; chunk += gridDim.x * 16) {
    const int n0 = chunk + wv * 4;
    const float* r0 = in + (size_t)n0 * CI;
    const float* r1 = r0 + CI;
    const float* r2 = r1 + CI;
    const float* r3 = r2 + CI;
    float a0 = 0.f, a1 = 0.f, a2 = 0.f, a3 = 0.f;
#pragma unroll 8
    for (int ci = 0; ci < CI; ++ci) {
      const float w = wl[ci * 64 + col];
      a0 = fmaf(r0[ci], w, a0);
      a1 = fmaf(r1[ci], w, a1);
      a2 = fmaf(r2[ci], w, a2);
      a3 = fmaf(r3[ci], w, a3);
    }
    const size_t o = (size_t)n0 * 64 + col;
    out[o]       = a0;
    out[o + 64]  = a1;
    out[o + 128] = a2;
    out[o + 192] = a3;
  }
}

// ------- fused CSR aggregation + finalize (+optional skip GEMM, in place) ----
// Unrolled by 4: 4 independent row-gathers in flight per wave (MLP x4).
template <bool SKIP>
__global__ __launch_bounds__(256) void k_agg(const float* __restrict__ hw,
                                             const float2* __restrict__ csr,
                                             const int* __restrict__ row_ptr,
                                             const float* __restrict__ dinv,
                                             const float* __restrict__ bias,
                                             const float* __restrict__ skipW,
                                             const float* __restrict__ skipB,
                                             float* __restrict__ h) {
  __shared__ float swl[SKIP ? 64 * 64 : 64];
  if (SKIP) {
    for (int i = threadIdx.x; i < 64 * 64; i += blockDim.x) swl[i] = skipW[i];
    __syncthreads();
  }
  const int col = threadIdx.x & 63;
  const int wv  = threadIdx.x >> 6;  // one wave == one node
  for (int n = blockIdx.x * 4 + wv; n < NN; n += gridDim.x * 4) {
    const int beg = row_ptr[n], end = row_ptr[n + 1];
    float a0 = 0.f, a1 = 0.f, a2 = 0.f, a3 = 0.f;
    int j = beg;
    for (; j + 4 <= end; j += 4) {
      const float2 p0 = csr[j + 0];
      const float2 p1 = csr[j + 1];
      const float2 p2 = csr[j + 2];
      const float2 p3 = csr[j + 3];
      const float v0 = hw[(size_t)__float_as_int(p0.x) * 64 + col];
      const float v1 = hw[(size_t)__float_as_int(p1.x) * 64 + col];
      const float v2 = hw[(size_t)__float_as_int(p2.x) * 64 + col];
      const float v3 = hw[(size_t)__float_as_int(p3.x) * 64 + col];
      a0 = fmaf(p0.y, v0, a0);
      a1 = fmaf(p1.y, v1, a1);
      a2 = fmaf(p2.y, v2, a2);
      a3 = fmaf(p3.y, v3, a3);
    }
    for (; j < end; ++j) {
      const float2 p = csr[j];
      a0 = fmaf(p.y, hw[(size_t)__float_as_int(p.x) * 64 + col], a0);
    }
    const float acc = (a0 + a1) + (a2 + a3);
    const size_t idx = (size_t)n * 64 + col;
    const float di = dinv[n];
    float v = fmaxf(acc + hw[idx] * di * di + bias[col], 0.0f);
    if (SKIP) {
      const float* row = h + (size_t)n * 64;
      float sk = skipB[col];
#pragma unroll 8
      for (int ci = 0; ci < 64; ++ci) sk = fmaf(row[ci], swl[ci * 64 + col], sk);
      v += sk;  // all lanes finished reading row before any lane stores
    }
    h[idx] = v;
  }
}

// -------- mean-pool: b is SORTED -> run-length accumulate, few atomics ------
__global__ __launch_bounds__(256) void k_pool(const float* __restrict__ h,
                                              const int* __restrict__ b,
                                              float* __restrict__ pool,
                                              float* __restrict__ cnt) {
  const int col = threadIdx.x & 63;
  const int wv  = threadIdx.x >> 6;
  const int node0 = (blockIdx.x * 4 + wv) * 64;  // 64 consecutive nodes per wave
  if (node0 >= NN) return;
  const int node1 = min(node0 + 64, NN);
  int gcur = b[node0];
  float acc = 0.f;
  float run = 0.f;
  for (int n = node0; n < node1; ++n) {
    const int g = b[n];  // wave-uniform broadcast load
    if (g != gcur) {
      atomicAdd(&pool[(size_t)gcur * 64 + col], acc);
      if (col == 0) atomicAdd(&cnt[gcur], run);
      gcur = g; acc = 0.f; run = 0.f;
    }
    acc += h[(size_t)n * 64 + col];
    run += 1.f;
  }
  atomicAdd(&pool[(size_t)gcur * 64 + col], acc);
  if (col == 0) atomicAdd(&cnt[gcur], run);
}

// ---------------- MLP head ----------------
__global__ __launch_bounds__(64) void k_head(const float* __restrict__ pool,
                                             const float* __restrict__ cnt,
                                             const float* __restrict__ lin1W,
                                             const float* __restrict__ lin1b,
                                             const float* __restrict__ lin2W,
                                             const float* __restrict__ lin2b,
                                             float* __restrict__ out) {
  const int g = blockIdx.x;
  const int lane = threadIdx.x;
  const float c = fmaxf(cnt[g], 1.0f);
  float r = 0.f;
  if (lane < 32) {
    float s = lin1b[lane];
    const float* p = pool + (size_t)g * 64;
#pragma unroll 8
    for (int ci = 0; ci < 64; ++ci) s = fmaf(p[ci] / c, lin1W[ci * 32 + lane], s);
    r = fmaxf(s, 0.0f) * lin2W[lane];
  }
  for (int off = 32; off > 0; off >>= 1) r += __shfl_down(r, off, 64);
  if (lane == 0) out[g] = r + lin2b[0];
}

extern "C" void kernel_launch(void* const* d_in, const int* in_sizes, int n_in,
                              void* d_out, int out_size, void* d_ws, size_t ws_size,
                              hipStream_t stream) {
  const float* x     = (const float*)d_in[0];
  const int*   src   = (const int*)d_in[1];            // e_idx[0]
  const int*   dst   = ((const int*)d_in[1]) + NE;     // e_idx[1]
  const int*   b     = (const int*)d_in[2];
  const float* w0    = (const float*)d_in[3];
  const float* b0    = (const float*)d_in[4];
  const float* convW = (const float*)d_in[5];
  const float* convB = (const float*)d_in[6];
  const float* skipW = (const float*)d_in[7];
  const float* skipB = (const float*)d_in[8];
  const float* lin1W = (const float*)d_in[9];
  const float* lin1b = (const float*)d_in[10];
  const float* lin2W = (const float*)d_in[11];
  const float* lin2b = (const float*)d_in[12];
  float* out = (float*)d_out;

  // ---- workspace layout (4-byte units, 102400-padded node arrays) ----
  char* w = (char*)d_ws;
  const size_t NPAD = 102400;
  int*    cnt     = (int*)w;                 w += NPAD * 4;
  float*  dinv    = (float*)w;               w += NPAD * 4;
  int*    row_ptr = (int*)w;                 w += NPAD * 4;   // NN+1 used
  int*    cursor  = (int*)w;                 w += NPAD * 4;
  int*    incl    = (int*)w;                 w += NPAD * 4;
  int*    bsum    = (int*)w;                 w += 512 * 4;
  int*    boff    = (int*)w;                 w += 512 * 4;
  float2* csr     = (float2*)w;              w += (size_t)NE * 8;
  float*  hA      = (float*)w;               w += (size_t)NN * 64 * 4;
  float*  hB      = (float*)w;               w += (size_t)NN * 64 * 4;
  float*  pool    = (float*)w;               w += (size_t)NG * 64 * 4;
  float*  pcnt    = (float*)w;               w += (size_t)NG * 4;

  const int EB = (NE + 255) / 256;

  // ---- CSR build (once per launch) ----
  hipMemsetAsync(cnt, 0, NN * sizeof(int), stream);
  k_hist<<<EB, 256, 0, stream>>>(dst, cnt);
  k_dinv<<<(NN + 255) / 256, 256, 0, stream>>>(cnt, dinv);
  k_scan_a<<<NB, SCAN_B, 0, stream>>>(cnt, incl, bsum);
  k_scan_b<<<1, 256, 0, stream>>>(bsum, boff);
  k_scan_c<<<NB, SCAN_B, 0, stream>>>(cnt, incl, boff, row_ptr, cursor);
  k_fill<<<EB, 256, 0, stream>>>(src, dst, dinv, cursor, csr);

  // ---- layer 0 ----
  k_gemm<NF><<<512, 256, 0, stream>>>(x, w0, hB);
  k_agg<false><<<2048, 256, 0, stream>>>(hB, csr, row_ptr, dinv, b0,
                                         nullptr, nullptr, hA);
  // ---- layers 1..2 (skip fused, in place on hA) ----
  for (int i = 0; i < 2; ++i) {
    k_gemm<H><<<512, 256, 0, stream>>>(hA, convW + (size_t)i * H * H, hB);
    k_agg<true><<<2048, 256, 0, stream>>>(hB, csr, row_ptr, dinv,
                                          convB + (size_t)i * H,
                                          skipW + (size_t)i * H * H,
                                          skipB + (size_t)i * H, hA);
  }

  // ---- mean pool + head ----
  hipMemsetAsync(pool, 0, ((size_t)NG * 64 + NG) * sizeof(float), stream);
  k_pool<<<(NN / 256) + 1, 256, 0, stream>>>(hA, b, pool, pcnt);
  k_head<<<NG, 64, 0, stream>>>(pool, pcnt, lin1W, lin1b, lin2W, lin2b, out);
}

// Round 4
// 584.078 us; speedup vs baseline: 2.6483x; 1.1839x over previous
//
#include <hip/hip_runtime.h>

#define NN 100000      // nodes
#define NE 1600000     // edges
#define NF 128         // input features
#define H  64          // hidden channels
#define NG 4096        // graphs
#define SCAN_B 512
#define NB ((NN + SCAN_B - 1) / SCAN_B)   // 196 scan blocks

// ---------------- degree histogram (int) ----------------
__global__ __launch_bounds__(256) void k_hist(const int* __restrict__ dst,
                                              int* __restrict__ cnt) {
  int e = blockIdx.x * blockDim.x + threadIdx.x;
  if (e < NE) atomicAdd(&cnt[dst[e]], 1);
}

__global__ __launch_bounds__(256) void k_dinv(const int* __restrict__ cnt,
                                              float* __restrict__ dinv) {
  int i = blockIdx.x * blockDim.x + threadIdx.x;
  if (i < NN) dinv[i] = 1.0f / sqrtf((float)cnt[i] + 1.0f);
}

// ---------------- 3-phase exclusive scan of cnt -> row_ptr ----------------
__global__ __launch_bounds__(SCAN_B) void k_scan_a(const int* __restrict__ cnt,
                                                   int* __restrict__ incl,
                                                   int* __restrict__ bsum) {
  __shared__ int sh[SCAN_B];
  const int i = blockIdx.x * SCAN_B + threadIdx.x;
  int v = (i < NN) ? cnt[i] : 0;
  sh[threadIdx.x] = v;
  __syncthreads();
  for (int off = 1; off < SCAN_B; off <<= 1) {
    int add = (threadIdx.x >= off) ? sh[threadIdx.x - off] : 0;
    __syncthreads();
    sh[threadIdx.x] += add;
    __syncthreads();
  }
  if (i < NN) incl[i] = sh[threadIdx.x];
  if (threadIdx.x == SCAN_B - 1) bsum[blockIdx.x] = sh[SCAN_B - 1];
}

__global__ __launch_bounds__(256) void k_scan_b(int* __restrict__ bsum,
                                                int* __restrict__ boff) {
  __shared__ int sh[256];
  const int t = threadIdx.x;
  int v = (t < NB) ? bsum[t] : 0;
  sh[t] = v;
  __syncthreads();
  for (int off = 1; off < 256; off <<= 1) {
    int add = (t >= off) ? sh[t - off] : 0;
    __syncthreads();
    sh[t] += add;
    __syncthreads();
  }
  if (t < NB) boff[t] = sh[t] - v;  // exclusive
}

__global__ __launch_bounds__(SCAN_B) void k_scan_c(const int* __restrict__ cnt,
                                                   const int* __restrict__ incl,
                                                   const int* __restrict__ boff,
                                                   int* __restrict__ row_ptr,
                                                   int* __restrict__ cursor) {
  const int i = blockIdx.x * SCAN_B + threadIdx.x;
  if (i < NN) {
    const int start = incl[i] + boff[blockIdx.x] - cnt[i];
    row_ptr[i] = start;
    cursor[i] = start;
  }
  if (i == 0) row_ptr[NN] = NE;
}

// ---------------- CSR fill: packed (src, coef) per slot ----------------
__global__ __launch_bounds__(256) void k_fill(const int* __restrict__ src,
                                              const int* __restrict__ dst,
                                              const float* __restrict__ dinv,
                                              int* __restrict__ cursor,
                                              float2* __restrict__ csr) {
  int e = blockIdx.x * blockDim.x + threadIdx.x;
  if (e < NE) {
    const int s = src[e], d = dst[e];
    const int pos = atomicAdd(&cursor[d], 1);
    csr[pos] = make_float2(__int_as_float(s), dinv[s] * dinv[d]);
  }
}

// ---- node GEMM: out[n,:] = in[n,:] @ W ; SK: outS[n,:] = in[n,:]@Ws + bs ----
// 8 nodes per wave, scalar (wave-uniform) row loads, weights in LDS.
// SK path may run IN PLACE (outS == in): each row is read fully by its owning
// wave before that wave stores to it; rows are wave-exclusive.
template <int CI, bool SK>
__global__ __launch_bounds__(256) void k_gemm(const float* in,
                                              const float* __restrict__ W,
                                              const float* __restrict__ Ws,
                                              const float* __restrict__ bs,
                                              float* __restrict__ out,
                                              float* outS) {
  __shared__ float wl[CI * 64 + (SK ? 64 * 64 : 0)];
  for (int i = threadIdx.x; i < CI * 64; i += 256) wl[i] = W[i];
  if (SK)
    for (int i = threadIdx.x; i < 64 * 64; i += 256) wl[CI * 64 + i] = Ws[i];
  __syncthreads();
  const int col = threadIdx.x & 63;
  const int wv  = threadIdx.x >> 6;
  const float sb = SK ? bs[col] : 0.0f;
  // 3125 chunks of 32 nodes (4 waves x 8) cover NN exactly.
  for (int chunk = blockIdx.x; chunk < NN / 32; chunk += gridDim.x) {
    const int n0 = chunk * 32 + wv * 8;
    const int base = __builtin_amdgcn_readfirstlane(n0 * CI);
    float a[8], s[8];
#pragma unroll
    for (int k = 0; k < 8; ++k) { a[k] = 0.0f; s[k] = sb; }
#pragma unroll 4
    for (int ci = 0; ci < CI; ++ci) {
      const float w = wl[ci * 64 + col];
      const float ws = SK ? wl[CI * 64 + ci * 64 + col] : 0.0f;
#pragma unroll
      for (int k = 0; k < 8; ++k) {
        const float r = in[base + k * CI + ci];  // scalar load (uniform addr)
        a[k] = fmaf(r, w, a[k]);
        if (SK) s[k] = fmaf(r, ws, s[k]);
      }
    }
#pragma unroll
    for (int k = 0; k < 8; ++k) {
      const size_t o = (size_t)(n0 + k) * 64 + col;
      out[o] = a[k];
      if (SK) outS[o] = s[k];
    }
  }
}

// ------- CSR aggregation + finalize: h = relu(agg + hw*di^2 + bias) [+ hs] ---
// 8 independent row-gathers in flight; csr streamed nontemporal.
// ADD_S path runs with hs == h (read then write same addr, same thread).
template <bool ADD_S>
__global__ __launch_bounds__(256) void k_agg(const float* __restrict__ hw,
                                             const float* hs,
                                             const unsigned long long* __restrict__ csr,
                                             const int* __restrict__ row_ptr,
                                             const float* __restrict__ dinv,
                                             const float* __restrict__ bias,
                                             float* h) {
  const int col = threadIdx.x & 63;
  const int wv  = threadIdx.x >> 6;
  const float brc = bias[col];
  for (int n = blockIdx.x * 4 + wv; n < NN; n += gridDim.x * 4) {
    const int beg = __builtin_amdgcn_readfirstlane(row_ptr[n]);
    const int end = __builtin_amdgcn_readfirstlane(row_ptr[n + 1]);
    float a[8];
#pragma unroll
    for (int k = 0; k < 8; ++k) a[k] = 0.0f;
    int j = beg;
    for (; j + 8 <= end; j += 8) {
      unsigned long long p[8];
      float v[8];
#pragma unroll
      for (int k = 0; k < 8; ++k) p[k] = __builtin_nontemporal_load(&csr[j + k]);
#pragma unroll
      for (int k = 0; k < 8; ++k)
        v[k] = hw[(size_t)(unsigned)(p[k] & 0xffffffffu) * 64 + col];
#pragma unroll
      for (int k = 0; k < 8; ++k)
        a[k] = fmaf(__uint_as_float((unsigned)(p[k] >> 32)), v[k], a[k]);
    }
    if (j + 4 <= end) {
      unsigned long long p[4];
      float v[4];
#pragma unroll
      for (int k = 0; k < 4; ++k) p[k] = __builtin_nontemporal_load(&csr[j + k]);
#pragma unroll
      for (int k = 0; k < 4; ++k)
        v[k] = hw[(size_t)(unsigned)(p[k] & 0xffffffffu) * 64 + col];
#pragma unroll
      for (int k = 0; k < 4; ++k)
        a[k] = fmaf(__uint_as_float((unsigned)(p[k] >> 32)), v[k], a[k]);
      j += 4;
    }
    if (j + 2 <= end) {
      unsigned long long p0 = __builtin_nontemporal_load(&csr[j]);
      unsigned long long p1 = __builtin_nontemporal_load(&csr[j + 1]);
      const float v0 = hw[(size_t)(unsigned)(p0 & 0xffffffffu) * 64 + col];
      const float v1 = hw[(size_t)(unsigned)(p1 & 0xffffffffu) * 64 + col];
      a[0] = fmaf(__uint_as_float((unsigned)(p0 >> 32)), v0, a[0]);
      a[1] = fmaf(__uint_as_float((unsigned)(p1 >> 32)), v1, a[1]);
      j += 2;
    }
    if (j < end) {
      unsigned long long p0 = __builtin_nontemporal_load(&csr[j]);
      a[0] = fmaf(__uint_as_float((unsigned)(p0 >> 32)),
                  hw[(size_t)(unsigned)(p0 & 0xffffffffu) * 64 + col], a[0]);
    }
    const float acc = ((a[0] + a[1]) + (a[2] + a[3])) + ((a[4] + a[5]) + (a[6] + a[7]));
    const size_t idx = (size_t)n * 64 + col;
    const float di = dinv[n];
    float v = fmaxf(acc + hw[idx] * di * di + brc, 0.0f);
    if (ADD_S) v += hs[idx];
    h[idx] = v;
  }
}

// -------- mean-pool: b is SORTED -> run-length accumulate, few atomics ------
__global__ __launch_bounds__(256) void k_pool(const float* __restrict__ h,
                                              const int* __restrict__ b,
                                              float* __restrict__ pool,
                                              float* __restrict__ cnt) {
  const int col = threadIdx.x & 63;
  const int wv  = threadIdx.x >> 6;
  const int node0 = (blockIdx.x * 4 + wv) * 64;  // 64 consecutive nodes per wave
  if (node0 >= NN) return;
  const int node1 = min(node0 + 64, NN);
  int gcur = b[node0];
  float acc = 0.f;
  float run = 0.f;
  for (int n = node0; n < node1; ++n) {
    const int g = b[n];  // wave-uniform broadcast load
    if (g != gcur) {
      atomicAdd(&pool[(size_t)gcur * 64 + col], acc);
      if (col == 0) atomicAdd(&cnt[gcur], run);
      gcur = g; acc = 0.f; run = 0.f;
    }
    acc += h[(size_t)n * 64 + col];
    run += 1.f;
  }
  atomicAdd(&pool[(size_t)gcur * 64 + col], acc);
  if (col == 0) atomicAdd(&cnt[gcur], run);
}

// ---------------- MLP head ----------------
__global__ __launch_bounds__(64) void k_head(const float* __restrict__ pool,
                                             const float* __restrict__ cnt,
                                             const float* __restrict__ lin1W,
                                             const float* __restrict__ lin1b,
                                             const float* __restrict__ lin2W,
                                             const float* __restrict__ lin2b,
                                             float* __restrict__ out) {
  const int g = blockIdx.x;
  const int lane = threadIdx.x;
  const float c = fmaxf(cnt[g], 1.0f);
  float r = 0.f;
  if (lane < 32) {
    float s = lin1b[lane];
    const float* p = pool + (size_t)g * 64;
#pragma unroll 8
    for (int ci = 0; ci < 64; ++ci) s = fmaf(p[ci] / c, lin1W[ci * 32 + lane], s);
    r = fmaxf(s, 0.0f) * lin2W[lane];
  }
  for (int off = 32; off > 0; off >>= 1) r += __shfl_down(r, off, 64);
  if (lane == 0) out[g] = r + lin2b[0];
}

extern "C" void kernel_launch(void* const* d_in, const int* in_sizes, int n_in,
                              void* d_out, int out_size, void* d_ws, size_t ws_size,
                              hipStream_t stream) {
  const float* x     = (const float*)d_in[0];
  const int*   src   = (const int*)d_in[1];            // e_idx[0]
  const int*   dst   = ((const int*)d_in[1]) + NE;     // e_idx[1]
  const int*   b     = (const int*)d_in[2];
  const float* w0    = (const float*)d_in[3];
  const float* b0    = (const float*)d_in[4];
  const float* convW = (const float*)d_in[5];
  const float* convB = (const float*)d_in[6];
  const float* skipW = (const float*)d_in[7];
  const float* skipB = (const float*)d_in[8];
  const float* lin1W = (const float*)d_in[9];
  const float* lin1b = (const float*)d_in[10];
  const float* lin2W = (const float*)d_in[11];
  const float* lin2b = (const float*)d_in[12];
  float* out = (float*)d_out;

  // ---- workspace layout (4-byte units, 102400-padded node arrays) ----
  char* w = (char*)d_ws;
  const size_t NPAD = 102400;
  int*    cnt     = (int*)w;                 w += NPAD * 4;
  float*  dinv    = (float*)w;               w += NPAD * 4;
  int*    row_ptr = (int*)w;                 w += NPAD * 4;   // NN+1 used
  int*    cursor  = (int*)w;                 w += NPAD * 4;
  int*    incl    = (int*)w;                 w += NPAD * 4;
  int*    bsum    = (int*)w;                 w += 512 * 4;
  int*    boff    = (int*)w;                 w += 512 * 4;
  float2* csr     = (float2*)w;              w += (size_t)NE * 8;
  float*  hA      = (float*)w;               w += (size_t)NN * 64 * 4;
  float*  hB      = (float*)w;               w += (size_t)NN * 64 * 4;
  float*  pool    = (float*)w;               w += (size_t)NG * 64 * 4;
  float*  pcnt    = (float*)w;               w += (size_t)NG * 4;

  const int EB = (NE + 255) / 256;

  // ---- CSR build (once per launch) ----
  hipMemsetAsync(cnt, 0, NN * sizeof(int), stream);
  k_hist<<<EB, 256, 0, stream>>>(dst, cnt);
  k_dinv<<<(NN + 255) / 256, 256, 0, stream>>>(cnt, dinv);
  k_scan_a<<<NB, SCAN_B, 0, stream>>>(cnt, incl, bsum);
  k_scan_b<<<1, 256, 0, stream>>>(bsum, boff);
  k_scan_c<<<NB, SCAN_B, 0, stream>>>(cnt, incl, boff, row_ptr, cursor);
  k_fill<<<EB, 256, 0, stream>>>(src, dst, dinv, cursor, csr);

  const unsigned long long* csru = (const unsigned long long*)csr;

  // ---- layer 0 ----
  k_gemm<NF, false><<<2048, 256, 0, stream>>>(x, w0, nullptr, nullptr, hB, nullptr);
  k_agg<false><<<2048, 256, 0, stream>>>(hB, nullptr, csru, row_ptr, dinv, b0, hA);
  // ---- layers 1..2 (conv+skip GEMMs fused; skip written in place into hA) ----
  for (int i = 0; i < 2; ++i) {
    k_gemm<H, true><<<2048, 256, 0, stream>>>(hA, convW + (size_t)i * H * H,
                                              skipW + (size_t)i * H * H,
                                              skipB + (size_t)i * H, hB, hA);
    k_agg<true><<<2048, 256, 0, stream>>>(hB, hA, csru, row_ptr, dinv,
                                          convB + (size_t)i * H, hA);
  }

  // ---- mean pool + head ----
  hipMemsetAsync(pool, 0, ((size_t)NG * 64 + NG) * sizeof(float), stream);
  k_pool<<<(NN / 256) + 1, 256, 0, stream>>>(hA, b, pool, pcnt);
  k_head<<<NG, 64, 0, stream>>>(pool, pcnt, lin1W, lin1b, lin2W, lin2b, out);
}